// Round 11
// baseline (249.983 us; speedup 1.0000x reference)
//
#include <hip/hip_runtime.h>

// QuantLinear: out[8,11008] = x[8,4096] @ W[11008,4096]^T
// packed[i] (INT32, one per byte!) holds 2 nibbles: low = weight 2i, high = weight 2i+1;
// weight = (q-8)*scale[idx/32]. 2048 int32 per row of 4096 k; 128 scales per row.
//
// R11: persistent WGs — ONE barrier per kernel, then a barrier-free pipelined task loop.
//   Diagnosis R5-R10: __syncthreads forces s_waitcnt vmcnt(0) (m97), draining all prefetch;
//   with 1 task/WG there was nothing to overlap. Fix: WG stays resident and runs 4 tasks.
//   Grid: 688 WGs x 256 thr, ALL co-resident (3 WGs/CU x 34 KB LDS; launch_bounds(256,3)).
//   WG w: quarter kq = (w&3)*1024 fixed -> stage x[8][1024] (32 KB) ONCE, 1 barrier.
//   Tasks i=0..3: row-group rg = (w>>2) + i*172 (16 rows; wave owns 4).
//   Pipeline: issue task i+1 loads (8x dwordx4 weights + 2 scale dwords, ping-pong regs),
//   then compute task i -> per-iteration vmcnt wait covers group i only; group i+1 in flight.
//   Scales park in wave-private LDS (same-wave DS order, no barrier needed).
//   Epilogue per task: 5-step shfl_xor tree + xor32; lanes 0-31 atomicAdd (out memset to 0).

#define OUT_F 11008
#define IN_F  4096

struct Pref {
    int4  wq[2][4];   // [k-tile][row]
    float sa, sb;     // lane-strided scales: rows {sr, sr+2}, blk sblk
};

__device__ __forceinline__ void issue_task(Pref& p,
                                           const int* __restrict__ packed,
                                           const float* __restrict__ scales,
                                           int r0, int kq, int lane)
{
    const int pb = r0 * 2048 + (kq >> 1) + lane * 4;   // int32 units; lane owns 8 k (int4)
#pragma unroll
    for (int t = 0; t < 2; ++t)
#pragma unroll
        for (int r = 0; r < 4; ++r)
            p.wq[t][r] = *(const int4*)(packed + pb + r * 2048 + t * 256);

    const int sr   = lane >> 5;                        // 0..1
    const int sblk = lane & 31;                        // 0..31
    p.sa = scales[(r0 + sr)     * 128 + (kq >> 5) + sblk];
    p.sb = scales[(r0 + 2 + sr) * 128 + (kq >> 5) + sblk];
}

__device__ __forceinline__ void compute_task(const Pref& p,
                                             float* __restrict__ swv,   // wave's 128-float park
                                             const float* __restrict__ xs,
                                             float* __restrict__ out,
                                             int r0, int lane)
{
    // park scales (wave-private LDS; same-wave DS ops are ordered, no barrier)
    swv[lane]      = p.sa;        // rows 0-1: index sr*32+sblk == lane
    swv[64 + lane] = p.sb;        // rows 2-3

    float acc[32];                // acc[r*8 + m]
#pragma unroll
    for (int i = 0; i < 32; ++i) acc[i] = 0.f;

#pragma unroll
    for (int t = 0; t < 2; ++t) { // 2 tiles of 512 k
        float w[4][8];
#pragma unroll
        for (int r = 0; r < 4; ++r) {
            const float s  = swv[r * 32 + t * 16 + (lane >> 2)];  // blk = kl/32
            const float ns = -8.f * s;
            const int4  q  = p.wq[t][r];
            w[r][0] = fmaf((float)(q.x & 15),        s, ns);
            w[r][1] = fmaf((float)((q.x >> 4) & 15), s, ns);
            w[r][2] = fmaf((float)(q.y & 15),        s, ns);
            w[r][3] = fmaf((float)((q.y >> 4) & 15), s, ns);
            w[r][4] = fmaf((float)(q.z & 15),        s, ns);
            w[r][5] = fmaf((float)((q.z >> 4) & 15), s, ns);
            w[r][6] = fmaf((float)(q.w & 15),        s, ns);
            w[r][7] = fmaf((float)((q.w >> 4) & 15), s, ns);
        }

        const int kl = t * 512 + lane * 8;            // local k (lane's 8 k)
#pragma unroll
        for (int m = 0; m < 8; ++m) {
            const float4 xa = *(const float4*)(xs + m * 1024 + kl);
            const float4 xb = *(const float4*)(xs + m * 1024 + kl + 4);
#pragma unroll
            for (int r = 0; r < 4; ++r) {
                float a = acc[r * 8 + m];
                a = fmaf(w[r][0], xa.x, a);
                a = fmaf(w[r][1], xa.y, a);
                a = fmaf(w[r][2], xa.z, a);
                a = fmaf(w[r][3], xa.w, a);
                a = fmaf(w[r][4], xb.x, a);
                a = fmaf(w[r][5], xb.y, a);
                a = fmaf(w[r][6], xb.z, a);
                a = fmaf(w[r][7], xb.w, a);
                acc[r * 8 + m] = a;
            }
        }
    }

    // merge tree: lane l ends with wave-total for index l&31 (r = (l&31)>>3, m = l&7)
#pragma unroll
    for (int s = 0; s < 5; ++s) {
        const int bit = (lane >> s) & 1;
        const int n = 16 >> s;
#pragma unroll
        for (int j = 0; j < n; ++j) {
            const float u = bit ? acc[2 * j + 1] : acc[2 * j];
            const float v = bit ? acc[2 * j]     : acc[2 * j + 1];
            acc[j] = u + __shfl_xor(v, 1 << s, 64);
        }
    }
    acc[0] += __shfl_xor(acc[0], 32, 64);

    if (lane < 32) {
        const int r = lane >> 3;
        const int m = lane & 7;
        atomicAdd(out + m * OUT_F + r0 + r, acc[0]);
    }
}

__global__ __launch_bounds__(256, 3) void qlin_kernel(
    const float* __restrict__ x,
    const int*   __restrict__ packed,
    const float* __restrict__ scales,
    float*       __restrict__ out)
{
    const int tid  = threadIdx.x;
    const int lane = tid & 63;
    const int wave = tid >> 6;
    const int w    = blockIdx.x;             // 0..687
    const int kq   = (w & 3) * 1024;         // fixed k-quarter for this WG
    const int rgb  = w >> 2;                 // 0..171; task i: rg = rgb + i*172

    __shared__ float xs[8 * 1024];           // staged x quarter (32 KB), read-only after barrier
    __shared__ float sws[4 * 128];           // per-wave scale parks (2 KB)

    // ---- x loads first (oldest in vmcnt queue) ----
    float4 xv[8];
    {
        const float* xg = x + kq;
#pragma unroll
        for (int i = 0; i < 8; ++i) {
            const int f  = tid + i * 256;
            const int m  = f >> 8;
            const int kv = (f & 255) << 2;
            xv[i] = *(const float4*)(xg + m * IN_F + kv);
        }
    }

    // ---- prefetch task 0 (rides out staging; the one barrier drains it, cost paid once) ----
    Pref A, B;
    const int r0_0 = (rgb + 0 * 172) * 16 + wave * 4;
    const int r0_1 = (rgb + 1 * 172) * 16 + wave * 4;
    const int r0_2 = (rgb + 2 * 172) * 16 + wave * 4;
    const int r0_3 = (rgb + 3 * 172) * 16 + wave * 4;
    issue_task(A, packed, scales, r0_0, kq, lane);

    // ---- stage x, single barrier of the whole kernel ----
#pragma unroll
    for (int i = 0; i < 8; ++i) {
        const int f  = tid + i * 256;
        const int m  = f >> 8;
        const int kv = (f & 255) << 2;
        *(float4*)(xs + m * 1024 + kv) = xv[i];
    }
    __syncthreads();

    float* swv = sws + wave * 128;

    // ---- barrier-free pipelined task loop (manually unrolled, ping-pong A/B) ----
    issue_task(B, packed, scales, r0_1, kq, lane);   // in flight during task 0
    compute_task(A, swv, xs, out, r0_0, lane);

    issue_task(A, packed, scales, r0_2, kq, lane);   // in flight during task 1
    compute_task(B, swv, xs, out, r0_1, lane);

    issue_task(B, packed, scales, r0_3, kq, lane);   // in flight during task 2
    compute_task(A, swv, xs, out, r0_2, lane);

    compute_task(B, swv, xs, out, r0_3, lane);
}

extern "C" void kernel_launch(void* const* d_in, const int* in_sizes, int n_in,
                              void* d_out, int out_size, void* d_ws, size_t ws_size,
                              hipStream_t stream) {
    const float* x      = (const float*)d_in[0];
    const int*   packed = (const int*)  d_in[1];
    const float* scales = (const float*)d_in[2];
    float*       out    = (float*)d_out;

    // split-K atomics accumulate into out -> zero it first (async, graph-capturable)
    hipMemsetAsync(out, 0, (size_t)out_size * sizeof(float), stream);

    dim3 grid(688), block(256);              // 688 persistent WGs, all co-resident
    hipLaunchKernelGGL(qlin_kernel, grid, block, 0, stream,
                       x, packed, scales, out);
}

// Round 12
// 145.219 us; speedup vs baseline: 1.7214x; 1.7214x over previous
//
#include <hip/hip_runtime.h>

// QuantLinear: out[8,11008] = x[8,4096] @ W[11008,4096]^T
// packed[i] (INT32, one per byte!) holds 2 nibbles: low = weight 2i, high = weight 2i+1;
// weight = (q-8)*scale[idx/32]. 2048 int32 per row of 4096 k; 128 scales per row.
//
// R12: NO LDS, NO barrier — the R5-R10 plateau was the __syncthreads vmcnt(0) drain +
//   WG-convoyed phases (and R11's persistent variant died of register spills: 175 MB scratch).
//   x comes from global per tile: each WG's 32 KB x-quarter-slice is L1/L2-resident.
//   In-order vmcnt pipeline per wave (4 tiles of 256 k):
//     W(0) X(0) W(1) | consume(0) X(1) W(2) | consume(1) X(2) W(3) | consume(2) X(3) | consume(3)
//   consume(t) waits on X(t); W(t+1) is NEWER in the queue so it stays in flight ->
//   every weight load gets >= 1 tile of compute + x-issue as latency cover, no full drain ever.
//   Grid: 688 row-groups x split-K=4 = 2752 WGs x 256 thr. Wave: 4 rows x 1024-k quarter.
//   Lane owns 4 consecutive k: weights int2 (512 B/wave-instr), x float4 (4 KB/wave-instr).
//   Flat registers: acc[32] + wqA/wqB (4x int2 each) + xr[8] float4 ~ 116 VGPR, bounds (256,4).
//   Epilogue: 5-step shfl_xor tree + xor32; lanes 0-31 atomicAdd (out memset to 0).

#define OUT_F 11008
#define IN_F  4096

__global__ __launch_bounds__(256, 4) void qlin_kernel(
    const float* __restrict__ x,
    const int*   __restrict__ packed,
    const float* __restrict__ scales,
    float*       __restrict__ out)
{
    const int tid  = threadIdx.x;
    const int lane = tid & 63;
    const int wave = tid >> 6;
    const int b    = blockIdx.x;
    const int q    = b & 3;                   // k-quarter
    const int g    = b >> 2;                  // row-group 0..687
    const int r0   = g * 16 + wave * 4;       // wave's 4 rows
    const int kq   = q * 1024;                // global k base of quarter

    // per-tile address bases (tile t adds t*128 dwords / t*8 scales / t*256 floats of x)
    const int pbase = r0 * 2048 + (kq >> 1) + lane * 2;   // int2 per row-tile
    const int sbase = r0 * 128 + (kq >> 5) + (lane >> 3); // lane's 4 k sit in one block
    const float* xb = x + kq + lane * 4;                  // float4 per m-tile

    float acc[32];                            // acc[r*8 + m]
#pragma unroll
    for (int i = 0; i < 32; ++i) acc[i] = 0.f;

    int2  wqA[4], wqB[4];
    float scA[4], scB[4];
    float4 xr[8];

    // ---- prologue: W(0), X(0), W(1) ----
#pragma unroll
    for (int r = 0; r < 4; ++r) {
        wqA[r] = *(const int2*)(packed + pbase + r * 2048);
        scA[r] = scales[sbase + r * 128];
    }
#pragma unroll
    for (int m = 0; m < 8; ++m) xr[m] = *(const float4*)(xb + m * IN_F);
#pragma unroll
    for (int r = 0; r < 4; ++r) {
        wqB[r] = *(const int2*)(packed + pbase + r * 2048 + 128);
        scB[r] = scales[sbase + r * 128 + 8];
    }

#pragma unroll
    for (int t = 0; t < 4; ++t) {
        // select current tile's buffers (compile-time: t is unrolled)
        const int2*  wq = (t & 1) ? wqB : wqA;
        const float* sc = (t & 1) ? scB : scA;

        // consume tile t: dequant then FMA against xr (waits X(t); W(t+1) stays in flight)
        float w[4][4];
#pragma unroll
        for (int r = 0; r < 4; ++r) {
            const int   px = wq[r].x, py = wq[r].y;
            const float s  = sc[r];
            const float ns = -8.f * s;
            w[r][0] = fmaf((float)(px & 15),        s, ns);
            w[r][1] = fmaf((float)((px >> 4) & 15), s, ns);
            w[r][2] = fmaf((float)(py & 15),        s, ns);
            w[r][3] = fmaf((float)((py >> 4) & 15), s, ns);
        }

        float4 xc[8];
#pragma unroll
        for (int m = 0; m < 8; ++m) xc[m] = xr[m];

        // issue X(t+1) into xr, then W(t+2) into the freed weight buffer
        if (t < 3) {
#pragma unroll
            for (int m = 0; m < 8; ++m)
                xr[m] = *(const float4*)(xb + m * IN_F + (t + 1) * 256);
        }
        if (t < 2) {
            int2*  wn = (t & 1) ? wqB : wqA;    // buffer just freed into xc? no: freed = current
            float* sn = (t & 1) ? scB : scA;
#pragma unroll
            for (int r = 0; r < 4; ++r) {
                wn[r] = *(const int2*)(packed + pbase + r * 2048 + (t + 2) * 128);
                sn[r] = scales[sbase + r * 128 + (t + 2) * 8];
            }
        }

#pragma unroll
        for (int m = 0; m < 8; ++m) {
            const float4 xa = xc[m];
#pragma unroll
            for (int r = 0; r < 4; ++r) {
                float a = acc[r * 8 + m];
                a = fmaf(w[r][0], xa.x, a);
                a = fmaf(w[r][1], xa.y, a);
                a = fmaf(w[r][2], xa.z, a);
                a = fmaf(w[r][3], xa.w, a);
                acc[r * 8 + m] = a;
            }
        }
    }

    // ---- merge tree over 32 values: lane l ends with wave-total for index l&31 ----
#pragma unroll
    for (int s = 0; s < 5; ++s) {
        const int bit = (lane >> s) & 1;
        const int n = 16 >> s;
#pragma unroll
        for (int j = 0; j < n; ++j) {
            const float u = bit ? acc[2 * j + 1] : acc[2 * j];
            const float v = bit ? acc[2 * j]     : acc[2 * j + 1];
            acc[j] = u + __shfl_xor(v, 1 << s, 64);
        }
    }
    acc[0] += __shfl_xor(acc[0], 32, 64);

    if (lane < 32) {
        const int r = lane >> 3;               // index l = r*8 + m
        const int m = lane & 7;
        atomicAdd(out + m * OUT_F + r0 + r, acc[0]);
    }
}

extern "C" void kernel_launch(void* const* d_in, const int* in_sizes, int n_in,
                              void* d_out, int out_size, void* d_ws, size_t ws_size,
                              hipStream_t stream) {
    const float* x      = (const float*)d_in[0];
    const int*   packed = (const int*)  d_in[1];
    const float* scales = (const float*)d_in[2];
    float*       out    = (float*)d_out;

    // split-K atomics accumulate into out -> zero it first (async, graph-capturable)
    hipMemsetAsync(out, 0, (size_t)out_size * sizeof(float), stream);

    dim3 grid((OUT_F / 16) * 4), block(256);   // 2752 WGs x 4 waves
    hipLaunchKernelGGL(qlin_kernel, grid, block, 0, stream,
                       x, packed, scales, out);
}

// Round 13
// 140.053 us; speedup vs baseline: 1.7849x; 1.0369x over previous
//
#include <hip/hip_runtime.h>

// QuantLinear: out[8,11008] = x[8,4096] @ W[11008,4096]^T
// packed[i] (INT32, one per byte!) holds 2 nibbles: low = weight 2i, high = weight 2i+1;
// weight = (q-8)*scale[idx/32]. 2048 int32 per row of 4096 k; 128 scales per row.
//
// R13: async global->LDS DMA (m97 pattern). Diagnosis R3-R12: the compiler SINKS register
//   prefetch loads to their uses to cut VGPR liveness (R4: VGPR=64 vs ~110 planned), so every
//   source-level pipeline re-serialized -> one exposed latency per batch -> ~2.5 TB/s cap.
//   __builtin_amdgcn_global_load_lds has NO VGPR destination: unsinkable, register-free.
//   WG = 256 thr: 16 rows x full K (no split-K -> no atomics, no memset). 16 tiles of 256 k,
//   double-buffered LDS: weights 8 KB + x 8 KB per buf, scales 8 KB staged once = 40 KB
//   -> 4 WGs/CU; barrier drains covered by cross-WG overlap (m114/m97-validated).
//   DMA: 16 B/lane; weight call stages 2 rows via split-lane per-lane sources (LDS dest is
//   wave-uniform base + lane*16 -- m104 -- so LDS layout is unpadded lane-linear).
//   Consume: weights ds_read_b64 (2-way free), x ds_read_b128, scales broadcast b32.
//   Epilogue: 5-step shfl_xor tree + xor32 -> 32 final outputs per wave, plain stores.

#define OUT_F 11008
#define IN_F  4096

__device__ __forceinline__ void dma16(const void* g, void* l) {
    __builtin_amdgcn_global_load_lds(
        (const __attribute__((address_space(1))) unsigned int*)g,
        (__attribute__((address_space(3))) unsigned int*)l, 16, 0, 0);
}

__global__ __launch_bounds__(256, 4) void qlin_kernel(
    const float* __restrict__ x,
    const int*   __restrict__ packed,
    const float* __restrict__ scales,
    float*       __restrict__ out)
{
    const int tid  = threadIdx.x;
    const int lane = tid & 63;
    const int wave = tid >> 6;
    const int r0   = blockIdx.x * 16;        // WG's 16 rows, full K

    __shared__ int   wl[2][16 * 128];        // [buf][row*128 + i]  (int32-format weights, 8 KB)
    __shared__ float xl[2][8 * 256];         // [buf][m*256 + k]    (8 KB)
    __shared__ float sl[16 * 128];           // [row*128 + blk]     (8 KB, staged once)

    // ---- prologue: stage all scales (8 chunks of 2 rows; rows contiguous in global) ----
    for (int c = wave; c < 8; c += 4)
        dma16(scales + (r0 + 2 * c) * 128 + lane * 4, &sl[c * 256]);

    // ---- stage tile 0 ----
    {
        const int t = 0, bf = 0;
        for (int c = wave; c < 8; c += 4) {          // weights: 2 rows per 1-KB call
            const int rr = 2 * c + (lane >> 5);      // per-lane row (split-lane source)
            const int lb = lane & 31;                // 16-B chunk within the row-tile (512 B)
            dma16(packed + (r0 + rr) * 2048 + t * 128 + lb * 4, &wl[bf][c * 256]);
        }
        for (int m = wave; m < 8; m += 4)            // x: one m-row (1 KB) per call
            dma16(x + m * IN_F + t * 256 + lane * 4, &xl[bf][m * 256]);
    }

    float acc[32];                           // acc[r*8 + m], wave's rows r0+4*wave+r
#pragma unroll
    for (int i = 0; i < 32; ++i) acc[i] = 0.f;

    for (int t = 0; t < 16; ++t) {
        // issue tile t+1 DMAs into the other buffer (unsinkable, register-free)
        if (t < 15) {
            const int tn = t + 1, bf = tn & 1;
            for (int c = wave; c < 8; c += 4) {
                const int rr = 2 * c + (lane >> 5);
                const int lb = lane & 31;
                dma16(packed + (r0 + rr) * 2048 + tn * 128 + lb * 4, &wl[bf][c * 256]);
            }
            for (int m = wave; m < 8; m += 4)
                dma16(x + m * IN_F + tn * 256 + lane * 4, &xl[bf][m * 256]);
        }

        __syncthreads();                     // drains DMAs for tile t (t+1 rides along)

        const int*   wb = wl[t & 1];
        const float* xb = xl[t & 1];

        // dequant wave's 4 rows x lane's 4 k (k = t*256 + lane*4 .. +4)
        float w[4][4];
#pragma unroll
        for (int r = 0; r < 4; ++r) {
            const int  rr = 4 * wave + r;
            const int2 p  = *(const int2*)(wb + rr * 128 + lane * 2);   // 2 int32 = 4 k
            const float s  = sl[rr * 128 + t * 8 + (lane >> 3)];        // blk = k/32
            const float ns = -8.f * s;
            w[r][0] = fmaf((float)(p.x & 15),        s, ns);
            w[r][1] = fmaf((float)((p.x >> 4) & 15), s, ns);
            w[r][2] = fmaf((float)(p.y & 15),        s, ns);
            w[r][3] = fmaf((float)((p.y >> 4) & 15), s, ns);
        }

#pragma unroll
        for (int m = 0; m < 8; ++m) {
            const float4 xa = *(const float4*)(xb + m * 256 + lane * 4); // ds_read_b128
#pragma unroll
            for (int r = 0; r < 4; ++r) {
                float a = acc[r * 8 + m];
                a = fmaf(w[r][0], xa.x, a);
                a = fmaf(w[r][1], xa.y, a);
                a = fmaf(w[r][2], xa.z, a);
                a = fmaf(w[r][3], xa.w, a);
                acc[r * 8 + m] = a;
            }
        }

        __syncthreads();                     // all waves done with buf[t&1] before t+2 overwrites
    }

    // ---- merge tree over 32 values: lane l ends with wave-total for index l&31 ----
#pragma unroll
    for (int s = 0; s < 5; ++s) {
        const int bit = (lane >> s) & 1;
        const int n = 16 >> s;
#pragma unroll
        for (int j = 0; j < n; ++j) {
            const float u = bit ? acc[2 * j + 1] : acc[2 * j];
            const float v = bit ? acc[2 * j]     : acc[2 * j + 1];
            acc[j] = u + __shfl_xor(v, 1 << s, 64);
        }
    }
    acc[0] += __shfl_xor(acc[0], 32, 64);

    // full-K sums -> plain stores, no atomics
    if (lane < 32) {
        const int r = lane >> 3;             // index l = r*8 + m
        const int m = lane & 7;
        out[m * OUT_F + r0 + 4 * wave + r] = acc[0];
    }
}

extern "C" void kernel_launch(void* const* d_in, const int* in_sizes, int n_in,
                              void* d_out, int out_size, void* d_ws, size_t ws_size,
                              hipStream_t stream) {
    const float* x      = (const float*)d_in[0];
    const int*   packed = (const int*)  d_in[1];
    const float* scales = (const float*)d_in[2];
    float*       out    = (float*)d_out;

    dim3 grid(OUT_F / 16), block(256);       // 688 WGs x 4 waves, full K per WG
    hipLaunchKernelGGL(qlin_kernel, grid, block, 0, stream,
                       x, packed, scales, out);
}